// Round 6
// baseline (87.718 us; speedup 1.0000x reference)
//
#include <hip/hip_runtime.h>
#include <math.h>

#define NCLS 91
#define FDIM 256
#define BINSZ (NCLS * FDIM)        // 23296

#define RPB 64                     // rows per mainpass block
#define W_SPAN 4                   // LDS window classes per block
#define SLICE_DW (1 + W_SPAN * FDIM + 15)  // 1041 -> pad to 1056 for alignment
#define SLICE_PAD 1056

// ---- workspace layout (4-byte units) ----
#define WS_HIST   BINSZ
#define WS_CURSOR (BINSZ + NCLS)
#define WS_SORTED (BINSZ + 2 * NCLS)

__device__ __forceinline__ float wave_sum64(float ss) {
    #pragma unroll
    for (int m = 1; m < 64; m <<= 1) ss += __shfl_xor(ss, m, 64);
    return ss;
}

// ---------------- K1: global label histogram ----------------
#define HT 256
extern "C" __global__ void __launch_bounds__(HT)
hist_k(const int* __restrict__ labels, unsigned int* __restrict__ hist, int nrows)
{
    __shared__ unsigned int lh[NCLS];
    const int tid = threadIdx.x;
    for (int i = tid; i < NCLS; i += HT) lh[i] = 0u;
    __syncthreads();
    for (int i = blockIdx.x * HT + tid; i < nrows; i += gridDim.x * HT)
        atomicAdd(&lh[labels[i]], 1u);
    __syncthreads();
    for (int i = tid; i < NCLS; i += HT)
        if (lh[i]) atomicAdd(&hist[i], lh[i]);
}

// ---------------- K2: exclusive prefix -> cursor ----------------
extern "C" __global__ void __launch_bounds__(128)
prefix_k(const unsigned int* __restrict__ hist, unsigned int* __restrict__ cursor)
{
    __shared__ unsigned int h[NCLS];
    const int tid = threadIdx.x;
    if (tid < NCLS) h[tid] = hist[tid];
    __syncthreads();
    if (tid == 0) {
        unsigned int s = 0;
        for (int c = 0; c < NCLS; ++c) { unsigned int v = h[c]; h[c] = s; s += v; }
    }
    __syncthreads();
    if (tid < NCLS) cursor[tid] = h[tid];
}

// ---------------- K3: counting-sort scatter ----------------
#define SCHUNK 1024
extern "C" __global__ void __launch_bounds__(HT)
scatter_k(const int* __restrict__ labels, unsigned int* __restrict__ cursor,
          unsigned int* __restrict__ sorted, int* __restrict__ slab, int nrows)
{
    __shared__ int ll[SCHUNK];
    __shared__ unsigned int lh[NCLS];
    __shared__ unsigned int base[NCLS];
    const int tid = threadIdx.x;
    const int c0 = blockIdx.x * SCHUNK;
    const int cn = min(SCHUNK, nrows - c0);
    if (cn <= 0) return;

    for (int i = tid; i < NCLS; i += HT) lh[i] = 0u;
    __syncthreads();
    for (int i = tid; i < cn; i += HT) {
        const int l = labels[c0 + i];
        ll[i] = l;
        atomicAdd(&lh[l], 1u);
    }
    __syncthreads();
    for (int i = tid; i < NCLS; i += HT) {
        const unsigned int n = lh[i];
        base[i] = n ? atomicAdd(&cursor[i], n) : 0u;
        lh[i] = 0u;
    }
    __syncthreads();
    for (int i = tid; i < cn; i += HT) {
        const int l = ll[i];
        const unsigned int rank = atomicAdd(&lh[l], 1u);
        const unsigned int pos = base[l] + rank;
        sorted[pos] = (unsigned int)(c0 + i);
        slab[pos] = l;
    }
}

// ---------------- K4: main pass ----------------
// 2048 blocks x 256 thr, 64 sorted rows/block (16/wave). Label-sorted rows ->
// block spans <=2 classes typically; accumulate into a 4-class LDS window
// (4KB -> 8 blocks/CU, FULL 32 waves/CU occupancy: TLP hides HBM latency,
// which R4's 1-block/CU 93KB-LDS layout could not). Block flushes the window
// to a private slice with plain stores; finalize reduces the ~23 contiguous
// slices per class. Global float atomics only on the never-taken fallback
// (window overflow under degenerate label skew).
#define MPT 256
extern "C" __global__ void __launch_bounds__(MPT)
mainpass(const float* __restrict__ feats, const unsigned int* __restrict__ sorted,
         const int* __restrict__ slab, float* __restrict__ g_sums,
         float* __restrict__ slices, int nrows)
{
    __shared__ float win[W_SPAN * FDIM];
    __shared__ int s_cmin;
    const int tid = threadIdx.x;
    const int blk0 = blockIdx.x * RPB;
    if (blk0 >= nrows) return;
    const int blk1 = min(nrows, blk0 + RPB);

    for (int i = tid; i < W_SPAN * FDIM; i += MPT) win[i] = 0.0f;
    if (tid == 0) s_cmin = slab[blk0];
    __syncthreads();
    const int cmin = s_cmin;

    const int lane = tid & 63;
    const int w = tid >> 6;
    const int i0w = min(blk1, blk0 + w * 16);
    const int i1w = min(blk1, i0w + 16);

    int pl = -1, pr = 0;
    if (lane < 16 && i0w + lane < i1w) {
        pl = slab[i0w + lane];
        pr = (int)sorted[i0w + lane];
    }

    float ax = 0.f, ay = 0.f, az = 0.f, aww = 0.f;
    int cur = -1;
    const int m = i1w - i0w;

    // flush helper: window if in span, else (degenerate) direct global atomic.
    // transposed slot layout: component k of lane -> slot k*64+lane (bank-clean)
    #define FLUSH(C)                                                          \
        do {                                                                  \
            const int slot_ = (C) - cmin;                                     \
            if (slot_ < W_SPAN) {                                             \
                float* b_ = win + slot_ * FDIM;                               \
                unsafeAtomicAdd(b_ + lane,       ax);                         \
                unsafeAtomicAdd(b_ + 64 + lane,  ay);                         \
                unsafeAtomicAdd(b_ + 128 + lane, az);                         \
                unsafeAtomicAdd(b_ + 192 + lane, aww);                        \
            } else {                                                          \
                float* g_ = g_sums + (C) * FDIM;                              \
                unsafeAtomicAdd(g_ + lane,       ax);                         \
                unsafeAtomicAdd(g_ + 64 + lane,  ay);                         \
                unsafeAtomicAdd(g_ + 128 + lane, az);                         \
                unsafeAtomicAdd(g_ + 192 + lane, aww);                        \
            }                                                                 \
        } while (0)

    for (int b0 = 0; b0 < m; b0 += 8) {
        const int n = min(8, m - b0);
        float4 v[8];
        int lj[8];
        #pragma unroll
        for (int j = 0; j < 8; ++j) {
            if (j < n) {
                const int r = __builtin_amdgcn_readfirstlane(__shfl(pr, b0 + j));
                lj[j] = __builtin_amdgcn_readfirstlane(__shfl(pl, b0 + j));
                v[j] = *reinterpret_cast<const float4*>(
                    feats + (size_t)r * FDIM + (size_t)lane * 4);
            }
        }
        #pragma unroll
        for (int j = 0; j < 8; ++j) {
            if (j < n) {
                if (lj[j] != cur) {                    // wave-uniform (scalar)
                    if (cur >= 0) FLUSH(cur);
                    ax = ay = az = aww = 0.f;
                    cur = lj[j];
                }
                const float ss = wave_sum64(v[j].x * v[j].x + v[j].y * v[j].y +
                                            v[j].z * v[j].z + v[j].w * v[j].w);
                const float inv = 1.0f / fmaxf(sqrtf(ss), 1e-12f);
                ax = fmaf(v[j].x, inv, ax);
                ay = fmaf(v[j].y, inv, ay);
                az = fmaf(v[j].z, inv, az);
                aww = fmaf(v[j].w, inv, aww);
            }
        }
    }
    if (cur >= 0) FLUSH(cur);
    #undef FLUSH

    __syncthreads();
    float* sl = slices + (size_t)blockIdx.x * SLICE_PAD;
    if (tid == 0) ((int*)sl)[0] = cmin;
    for (int i = tid; i < W_SPAN * FDIM; i += MPT) sl[1 + i] = win[i];
}

// ---------------- bool / scalar dtype detection ----------------
__device__ int detect_bool_enc(const void* p) {
    const unsigned int* u = (const unsigned int*)p;
    bool i32ok = true, f32ok = true;
    for (int i = 0; i < 22; ++i) {
        unsigned int w = u[i];
        if (w > 1u) i32ok = false;
        if (w != 0u && w != 0x3F800000u) f32ok = false;
    }
    return i32ok ? 1 : (f32ok ? 2 : 0);
}
__device__ bool read_bool(const void* p, int enc, int i) {
    if (enc == 1) return ((const unsigned int*)p)[i] != 0u;
    if (enc == 2) return ((const float*)p)[i] != 0.0f;
    return ((const unsigned char*)p)[i] != 0;
}
__device__ int read_step(const void* p) {
    unsigned int w = ((const unsigned int*)p)[0];
    int iv = (int)w;
    if (iv >= 0 && iv < 16777216) return iv;
    return (int)__uint_as_float(w);
}

// ---------------- K5: reduce slices + per-class finalize ----------------
extern "C" __global__ void __launch_bounds__(FDIM)
finalize(const float* __restrict__ g_sums, const unsigned int* __restrict__ hist,
         const unsigned int* __restrict__ cursor, const float* __restrict__ slices,
         const float* __restrict__ protos, const void* __restrict__ p_init,
         const float* __restrict__ p_var, const float* __restrict__ shadow,
         const void* __restrict__ s_init, const int* __restrict__ p_count,
         const void* __restrict__ p_step, float* __restrict__ out)
{
    const int c = blockIdx.x;
    const int d = threadIdx.x;

    __shared__ int enc_pi, enc_si;
    __shared__ float red[FDIM / 64];
    __shared__ float s_upd;
    if (d == 0) { enc_pi = detect_bool_enc(p_init); enc_si = detect_bool_enc(s_init); }
    __syncthreads();

    const int perm = ((d & 3) << 6) + (d >> 2);     // un-permute transposed slots
    const unsigned int cnt = hist[c];
    const bool present = cnt > 0u;

    float sum = g_sums[c * FDIM + perm];            // fallback-atomic contributions
    if (present) {
        const unsigned int E = cursor[c];           // after scatter: end offset
        const int bs = (int)((E - cnt) >> 6);       // RPB = 64
        const int be = (int)((E - 1) >> 6);
        for (int b = bs; b <= be; ++b) {
            const float* sl = slices + (size_t)b * SLICE_PAD;
            const int slot = c - ((const int*)sl)[0];
            if (slot >= 0 && slot < W_SPAN)
                sum += sl[1 + slot * FDIM + perm];
        }
    }

    const float cls = sum / fmaxf((float)cnt, 1.0f);
    const float oldp = protos[c * FDIM + d];

    const float diff = cls - oldp;
    float ds = wave_sum64(diff * diff);
    if ((d & 63) == 0) red[d >> 6] = ds;
    __syncthreads();
    if (d == 0) s_upd = sqrtf(red[0] + red[1] + red[2] + red[3] + 1e-24f);
    __syncthreads();
    const float upd_mag = s_upd;

    const bool  init  = read_bool(p_init, enc_pi, c);
    const bool  sinit = read_bool(s_init, enc_si, c);
    const float var   = p_var[c];
    const int   step  = read_step(p_step);

    const float progress = fminf(1.0f, (float)step * (1.0f / 2000.0f));
    const float mom = init ? (0.99f + 0.009f * expf(-var) * progress) : 0.99f;

    const float ema   = mom * oldp + (1.0f - mom) * cls;
    const float newp  = present ? (init ? ema : cls) : oldp;

    const float sh     = shadow[c * FDIM + d];
    const float sh_ema = 0.9999f * sh + 0.0001f * newp;
    const float newsh  = present ? (sinit ? sh_ema : newp) : sh;

    const int O1 = NCLS * FDIM;
    const int O2 = O1 + NCLS;
    const int O3 = O2 + NCLS * FDIM;
    const int O4 = O3 + NCLS;
    const int O5 = O4 + NCLS;

    out[c * FDIM + d]       = newp;
    out[O2 + c * FDIM + d]  = newsh;
    if (d == 0) {
        const float newvar = (present && init) ? (0.99f * var + 0.01f * upd_mag) : var;
        out[O1 + c] = newvar;
        out[O3 + c] = (init || present)  ? 1.0f : 0.0f;
        out[O4 + c] = (sinit || present) ? 1.0f : 0.0f;
        out[O5 + c] = (float)(p_count[c] + (present ? 1 : 0));
    }
}

extern "C" void kernel_launch(void* const* d_in, const int* in_sizes, int n_in,
                              void* d_out, int out_size, void* d_ws, size_t ws_size,
                              hipStream_t stream) {
    const float* feats  = (const float*)d_in[0];
    const int*   labels = (const int*)d_in[1];
    const float* protos = (const float*)d_in[2];
    const void*  p_init = d_in[3];
    const float* p_var  = (const float*)d_in[4];
    const float* shadow = (const float*)d_in[5];
    const void*  s_init = d_in[6];
    const int*   p_cnt  = (const int*)d_in[7];
    const void*  p_step = d_in[8];
    const int nrows = in_sizes[1];

    float*        g_sums = (float*)d_ws;
    unsigned int* hist   = (unsigned int*)d_ws + WS_HIST;
    unsigned int* cursor = (unsigned int*)d_ws + WS_CURSOR;
    unsigned int* sorted = (unsigned int*)d_ws + WS_SORTED;
    int*          slab   = (int*)((unsigned int*)d_ws + WS_SORTED + nrows);
    float*        slices = (float*)((unsigned int*)d_ws + WS_SORTED + 2 * nrows);

    hipMemsetAsync(d_ws, 0, (size_t)(BINSZ + 2 * NCLS) * 4, stream);

    hist_k<<<128, HT, 0, stream>>>(labels, hist, nrows);
    prefix_k<<<1, 128, 0, stream>>>(hist, cursor);
    const int scat_blocks = (nrows + SCHUNK - 1) / SCHUNK;
    scatter_k<<<scat_blocks, HT, 0, stream>>>(labels, cursor, sorted, slab, nrows);
    const int main_blocks = (nrows + RPB - 1) / RPB;
    mainpass<<<main_blocks, MPT, 0, stream>>>(feats, sorted, slab, g_sums, slices, nrows);
    finalize<<<NCLS, FDIM, 0, stream>>>(g_sums, hist, cursor, slices, protos, p_init,
                                        p_var, shadow, s_init, p_cnt, p_step, (float*)d_out);
}

// Round 7
// 77.265 us; speedup vs baseline: 1.1353x; 1.1353x over previous
//
#include <hip/hip_runtime.h>
#include <math.h>

#define NCLS 91
#define FDIM 256
#define BINSZ (NCLS * FDIM)        // 23296

// ---- workspace layout (4-byte units) ----
#define WS_HIST   BINSZ            // 96 (padded)
#define WS_CURSOR (BINSZ + 96)     // 96
#define WS_HPART  (BINSZ + 192)    // 128 * 96
#define WS_PACKED (BINSZ + 192 + 128 * 96)   // uint2 per row

#define HBLK 128                   // hist/scatter grid
#define SCHUNK 1024

__device__ __forceinline__ float wave_sum64(float ss) {
    #pragma unroll
    for (int m = 1; m < 64; m <<= 1) ss += __shfl_xor(ss, m, 64);
    return ss;
}

// ---------------- K1: per-block label histogram (plain stores) + zero g_sums ----------------
#define HT 256
extern "C" __global__ void __launch_bounds__(HT)
hist_k(const int* __restrict__ labels, unsigned int* __restrict__ hpart,
       float* __restrict__ g_sums, int nrows)
{
    __shared__ unsigned int lh[NCLS];
    const int tid = threadIdx.x;
    // fold g_sums zeroing in here (128 blocks x 182 = 23296 exactly)
    const int z0 = blockIdx.x * 182;
    if (tid < 182 && z0 + tid < BINSZ) g_sums[z0 + tid] = 0.0f;
    for (int i = tid; i < NCLS; i += HT) lh[i] = 0u;
    __syncthreads();
    for (int i = blockIdx.x * HT + tid; i < nrows; i += gridDim.x * HT)
        atomicAdd(&lh[labels[i]], 1u);
    __syncthreads();
    for (int i = tid; i < NCLS; i += HT)
        hpart[blockIdx.x * 96 + i] = lh[i];
}

// ---------------- K2: reduce parts -> hist, exclusive prefix -> cursor ----------------
extern "C" __global__ void __launch_bounds__(128)
prefix_k(const unsigned int* __restrict__ hpart, unsigned int* __restrict__ hist,
         unsigned int* __restrict__ cursor, int nparts)
{
    __shared__ unsigned int h[NCLS];
    const int t = threadIdx.x;
    if (t < NCLS) {
        unsigned int s = 0;
        for (int p = 0; p < nparts; ++p) s += hpart[p * 96 + t];
        h[t] = s;
        hist[t] = s;
    }
    __syncthreads();
    if (t == 0) {
        unsigned int s = 0;
        for (int c = 0; c < NCLS; ++c) { unsigned int v = h[c]; h[c] = s; s += v; }
    }
    __syncthreads();
    if (t < NCLS) cursor[t] = h[t];
}

// ---------------- K3: counting-sort scatter -> packed (row,label) uint2 ----------------
extern "C" __global__ void __launch_bounds__(HT)
scatter_k(const int* __restrict__ labels, unsigned int* __restrict__ cursor,
          uint2* __restrict__ packed, int nrows)
{
    __shared__ int ll[SCHUNK];
    __shared__ unsigned int lh[NCLS];
    __shared__ unsigned int base[NCLS];
    const int tid = threadIdx.x;
    const int c0 = blockIdx.x * SCHUNK;
    const int cn = min(SCHUNK, nrows - c0);
    if (cn <= 0) return;

    for (int i = tid; i < NCLS; i += HT) lh[i] = 0u;
    __syncthreads();
    for (int i = tid; i < cn; i += HT) {
        const int l = labels[c0 + i];
        ll[i] = l;
        atomicAdd(&lh[l], 1u);
    }
    __syncthreads();
    for (int i = tid; i < NCLS; i += HT) {
        const unsigned int n = lh[i];
        base[i] = n ? atomicAdd(&cursor[i], n) : 0u;
        lh[i] = 0u;
    }
    __syncthreads();
    for (int i = tid; i < cn; i += HT) {
        const int l = ll[i];
        const unsigned int rank = atomicAdd(&lh[l], 1u);
        packed[base[l] + rank] = make_uint2((unsigned int)(c0 + i), (unsigned int)l);
    }
}

// ---------------- K4: main pass ----------------
// R4 skeleton (256 blocks x 1024 thr, 512 sorted rows/block, full 93KB LDS bins,
// span-atomic flush) + forced 2-deep x 8-wide load pipeline (ping-pong va/vb:
// dataflow keeps 16 float4 live -> compiler cannot serialize, unlike R5's
// VGPR=36 version) + uniform-label fast path (sorted labels: ~98% of waves see
// ONE class -> no per-row label shfl, one bin flush per wave).
#define MPT 1024
#define RPW 32                      // rows per wave
#define RPB 512                     // rows per block (16 waves)

__device__ __forceinline__ void load8(const float* __restrict__ feats, int pr,
                                      int b0, size_t lofs, float4 (&v)[8]) {
    #pragma unroll
    for (int j = 0; j < 8; ++j) {
        const int r = __builtin_amdgcn_readfirstlane(__shfl(pr, b0 + j, 64));
        v[j] = *reinterpret_cast<const float4*>(feats + (size_t)r * FDIM + lofs);
    }
}
__device__ __forceinline__ void proc8(const float4 (&v)[8], float& ax, float& ay,
                                      float& az, float& aw) {
    #pragma unroll
    for (int j = 0; j < 8; ++j) {
        const float ss = wave_sum64(v[j].x * v[j].x + v[j].y * v[j].y +
                                    v[j].z * v[j].z + v[j].w * v[j].w);
        const float inv = 1.0f / fmaxf(sqrtf(ss), 1e-12f);
        ax = fmaf(v[j].x, inv, ax); ay = fmaf(v[j].y, inv, ay);
        az = fmaf(v[j].z, inv, az); aw = fmaf(v[j].w, inv, aw);
    }
}
__device__ __forceinline__ void flush_bins(float* bins, int c, int lane,
                                           float ax, float ay, float az, float aw) {
    float* b = bins + c * FDIM;     // transposed slots: comp k of lane l -> k*64+l
    unsafeAtomicAdd(b + lane,       ax);
    unsafeAtomicAdd(b + 64 + lane,  ay);
    unsafeAtomicAdd(b + 128 + lane, az);
    unsafeAtomicAdd(b + 192 + lane, aw);
}

extern "C" __global__ void __launch_bounds__(MPT)
mainpass(const float* __restrict__ feats, const uint2* __restrict__ packed,
         float* __restrict__ g_sums, int nrows)
{
    __shared__ float bins[BINSZ];
    __shared__ int s_cmin, s_cmax;
    const int tid = threadIdx.x;
    const int blk0 = blockIdx.x * RPB;
    if (blk0 >= nrows) return;
    const int blk1 = min(nrows, blk0 + RPB);

    for (int i = tid; i < BINSZ; i += MPT) bins[i] = 0.0f;
    if (tid == 0) { s_cmin = (int)packed[blk0].y; s_cmax = (int)packed[blk1 - 1].y; }
    __syncthreads();

    const int lane = tid & 63;
    const int w = tid >> 6;
    const int i0w = min(blk1, blk0 + w * RPW);
    const int i1w = min(blk1, i0w + RPW);
    const size_t lofs = (size_t)lane * 4;
    const int m = i1w - i0w;

    if (m > 0) {
        int pr = 0, pl = -1;
        if (lane < m) {
            const uint2 e = packed[i0w + lane];
            pr = (int)e.x; pl = (int)e.y;
        }
        const int lfirst = __builtin_amdgcn_readfirstlane(__shfl(pl, 0, 64));
        const int llast  = __builtin_amdgcn_readfirstlane(__shfl(pl, m - 1, 64));
        float ax = 0.f, ay = 0.f, az = 0.f, aw = 0.f;

        if (m == RPW && lfirst == llast) {
            // fast path: one class, 2-deep x 8-wide pipelined loads
            float4 va[8], vb[8];
            load8(feats, pr, 0,  lofs, va);
            load8(feats, pr, 8,  lofs, vb);
            proc8(va, ax, ay, az, aw);
            load8(feats, pr, 16, lofs, va);
            proc8(vb, ax, ay, az, aw);
            load8(feats, pr, 24, lofs, vb);
            proc8(va, ax, ay, az, aw);
            proc8(vb, ax, ay, az, aw);
            flush_bins(bins, lfirst, lane, ax, ay, az, aw);
        } else {
            // slow path (~2% of waves: label transition or tail)
            int cur = -1;
            for (int t = 0; t < m; ++t) {
                const int r   = __builtin_amdgcn_readfirstlane(__shfl(pr, t, 64));
                const int lab = __builtin_amdgcn_readfirstlane(__shfl(pl, t, 64));
                if (lab != cur) {
                    if (cur >= 0) flush_bins(bins, cur, lane, ax, ay, az, aw);
                    ax = ay = az = aw = 0.f;
                    cur = lab;
                }
                const float4 v = *reinterpret_cast<const float4*>(
                    feats + (size_t)r * FDIM + lofs);
                const float ss = wave_sum64(v.x * v.x + v.y * v.y + v.z * v.z + v.w * v.w);
                const float inv = 1.0f / fmaxf(sqrtf(ss), 1e-12f);
                ax = fmaf(v.x, inv, ax); ay = fmaf(v.y, inv, ay);
                az = fmaf(v.z, inv, az); aw = fmaf(v.w, inv, aw);
            }
            if (cur >= 0) flush_bins(bins, cur, lane, ax, ay, az, aw);
        }
    }

    __syncthreads();
    // sparse span flush: only classes this block touched (~2-3 of 91)
    const int cmin = s_cmin, cmax = s_cmax;
    const int base = cmin * FDIM;
    const int tot = (cmax - cmin + 1) * FDIM;
    for (int i = tid; i < tot; i += MPT) {
        const float vv = bins[base + i];
        if (vv != 0.0f) unsafeAtomicAdd(&g_sums[base + i], vv);
    }
}

// ---------------- bool / scalar dtype detection ----------------
__device__ int detect_bool_enc(const void* p) {
    const unsigned int* u = (const unsigned int*)p;
    bool i32ok = true, f32ok = true;
    for (int i = 0; i < 22; ++i) {
        unsigned int w = u[i];
        if (w > 1u) i32ok = false;
        if (w != 0u && w != 0x3F800000u) f32ok = false;
    }
    return i32ok ? 1 : (f32ok ? 2 : 0);
}
__device__ bool read_bool(const void* p, int enc, int i) {
    if (enc == 1) return ((const unsigned int*)p)[i] != 0u;
    if (enc == 2) return ((const float*)p)[i] != 0.0f;
    return ((const unsigned char*)p)[i] != 0;
}
__device__ int read_step(const void* p) {
    unsigned int w = ((const unsigned int*)p)[0];
    int iv = (int)w;
    if (iv >= 0 && iv < 16777216) return iv;
    return (int)__uint_as_float(w);
}

// ---------------- K5: per-class finalize (reads g_sums directly) ----------------
extern "C" __global__ void __launch_bounds__(FDIM)
finalize(const float* __restrict__ g_sums, const unsigned int* __restrict__ hist,
         const float* __restrict__ protos, const void* __restrict__ p_init,
         const float* __restrict__ p_var, const float* __restrict__ shadow,
         const void* __restrict__ s_init, const int* __restrict__ p_count,
         const void* __restrict__ p_step, float* __restrict__ out)
{
    const int c = blockIdx.x;
    const int d = threadIdx.x;

    __shared__ int enc_pi, enc_si;
    __shared__ float red[FDIM / 64];
    __shared__ float s_upd;
    if (d == 0) { enc_pi = detect_bool_enc(p_init); enc_si = detect_bool_enc(s_init); }
    __syncthreads();

    const unsigned int cnt = hist[c];
    const bool present = cnt > 0u;
    // un-permute transposed slots: element d at slot (d&3)*64 + (d>>2)
    const float sum = g_sums[c * FDIM + ((d & 3) << 6) + (d >> 2)];
    const float cls = sum / fmaxf((float)cnt, 1.0f);
    const float oldp = protos[c * FDIM + d];

    const float diff = cls - oldp;
    float ds = wave_sum64(diff * diff);
    if ((d & 63) == 0) red[d >> 6] = ds;
    __syncthreads();
    if (d == 0) s_upd = sqrtf(red[0] + red[1] + red[2] + red[3] + 1e-24f);
    __syncthreads();
    const float upd_mag = s_upd;

    const bool  init  = read_bool(p_init, enc_pi, c);
    const bool  sinit = read_bool(s_init, enc_si, c);
    const float var   = p_var[c];
    const int   step  = read_step(p_step);

    const float progress = fminf(1.0f, (float)step * (1.0f / 2000.0f));
    const float mom = init ? (0.99f + 0.009f * expf(-var) * progress) : 0.99f;

    const float ema   = mom * oldp + (1.0f - mom) * cls;
    const float newp  = present ? (init ? ema : cls) : oldp;

    const float sh     = shadow[c * FDIM + d];
    const float sh_ema = 0.9999f * sh + 0.0001f * newp;
    const float newsh  = present ? (sinit ? sh_ema : newp) : sh;

    const int O1 = NCLS * FDIM;
    const int O2 = O1 + NCLS;
    const int O3 = O2 + NCLS * FDIM;
    const int O4 = O3 + NCLS;
    const int O5 = O4 + NCLS;

    out[c * FDIM + d]       = newp;
    out[O2 + c * FDIM + d]  = newsh;
    if (d == 0) {
        const float newvar = (present && init) ? (0.99f * var + 0.01f * upd_mag) : var;
        out[O1 + c] = newvar;
        out[O3 + c] = (init || present)  ? 1.0f : 0.0f;
        out[O4 + c] = (sinit || present) ? 1.0f : 0.0f;
        out[O5 + c] = (float)(p_count[c] + (present ? 1 : 0));
    }
}

extern "C" void kernel_launch(void* const* d_in, const int* in_sizes, int n_in,
                              void* d_out, int out_size, void* d_ws, size_t ws_size,
                              hipStream_t stream) {
    const float* feats  = (const float*)d_in[0];
    const int*   labels = (const int*)d_in[1];
    const float* protos = (const float*)d_in[2];
    const void*  p_init = d_in[3];
    const float* p_var  = (const float*)d_in[4];
    const float* shadow = (const float*)d_in[5];
    const void*  s_init = d_in[6];
    const int*   p_cnt  = (const int*)d_in[7];
    const void*  p_step = d_in[8];
    const int nrows = in_sizes[1];

    float*        g_sums = (float*)d_ws;
    unsigned int* hist   = (unsigned int*)d_ws + WS_HIST;
    unsigned int* cursor = (unsigned int*)d_ws + WS_CURSOR;
    unsigned int* hpart  = (unsigned int*)d_ws + WS_HPART;
    uint2*        packed = (uint2*)((unsigned int*)d_ws + WS_PACKED);

    hist_k<<<HBLK, HT, 0, stream>>>(labels, hpart, g_sums, nrows);
    prefix_k<<<1, 128, 0, stream>>>(hpart, hist, cursor, HBLK);
    const int scat_blocks = (nrows + SCHUNK - 1) / SCHUNK;
    scatter_k<<<scat_blocks, HT, 0, stream>>>(labels, cursor, packed, nrows);
    const int main_blocks = (nrows + RPB - 1) / RPB;
    mainpass<<<main_blocks, MPT, 0, stream>>>(feats, packed, g_sums, nrows);
    finalize<<<NCLS, FDIM, 0, stream>>>(g_sums, hist, protos, p_init, p_var,
                                        shadow, s_init, p_cnt, p_step, (float*)d_out);
}